// Round 18
// baseline (236.042 us; speedup 1.0000x reference)
//
#include <hip/hip_runtime.h>
#include <hip/hip_bf16.h>
#include <math.h>

#define NROWS 8192
#define DDIM  10000
#define NCLS  100

#define KSPLIT 8
#define KS64   157            // 10048/64 k64-steps total
#define BM 128
#define UPD_DC 128            // dims per scatter block (lane = float2)
#define UPD_NY 8              // row-chunks
#define DPAD 10048

#define SCORES_N (NROWS*NCLS)
#define NCHUNK8 1256          // k-octets, padded to 10048
#define BP_CHUNKS (NCHUNK8*128)
#define PREPB_BLOCKS ((BP_CHUNKS + 255) / 256)

// ws layout in float (4B) units
#define WS_NORMCLS 0                                   // 128
#define WS_NRM     128                                 // KSPLIT*NROWS
#define WS_SCP     (WS_NRM + KSPLIT*NROWS)             // KSPLIT*NROWS*NCLS
#define WS_TP      (WS_SCP + KSPLIT*SCORES_N)          // NROWS ints (packed tgt<<8|pred or -1)
#define WS_BPH     (WS_TP + NROWS + 128)               // BP_CHUNKS*4 floats (8 f16 each)
#define WS_BPL     (WS_BPH + BP_CHUNKS*4)
#define WS_PART    (WS_BPL + BP_CHUNKS*4)              // UPD_NY * NCLS * DPAD floats

typedef _Float16 f16;
typedef f16 f16x8 __attribute__((ext_vector_type(8)));
typedef float f32x4 __attribute__((ext_vector_type(4)));

#define SBAR()  __builtin_amdgcn_s_barrier()
#define SCHED() __builtin_amdgcn_sched_barrier(0)

// ---------------- Phase 0 (fused): class norms + B prep ----------------
__global__ __launch_bounds__(256) void prep(const float* __restrict__ cls,
                                            float* __restrict__ ws)
{
    int bx = blockIdx.x;
    if (bx < NCLS) {
        int c = bx;
        const float* row = cls + (size_t)c * DDIM;
        float s = 0.f;
        for (int d = threadIdx.x; d < DDIM; d += 256) {
            float v = row[d];
            s = fmaf(v, v, s);
        }
        #pragma unroll
        for (int off = 32; off; off >>= 1) s += __shfl_xor(s, off, 64);
        __shared__ float red[4];
        int w = threadIdx.x >> 6, l = threadIdx.x & 63;
        if (l == 0) red[w] = s;
        __syncthreads();
        if (threadIdx.x == 0) {
            float t = red[0] + red[1] + red[2] + red[3];
            ws[WS_NORMCLS + c] = sqrtf(t);
        }
    } else {
        int c = (bx - NCLS) * 256 + threadIdx.x;
        if (c >= BP_CHUNKS) return;
        int col = c & 127, k8 = c >> 7;
        f16x8 hi, lo;
        #pragma unroll
        for (int j = 0; j < 8; ++j) {
            int k = k8 * 8 + j;
            float v = (col < NCLS && k < DDIM) ? cls[(size_t)col * DDIM + k] : 0.f;
            f16 h = (f16)v;
            hi[j] = h;
            lo[j] = (f16)(v - (float)h);
        }
        ((f16x8*)(ws + WS_BPH))[c] = hi;
        ((f16x8*)(ws + WS_BPL))[c] = lo;
    }
}

// ---------------- Phase 1: MFMA GEMM, BK=64 per stage (identical to R9) ----------------
__global__ __launch_bounds__(256, 2) void gemm_mfma(const float* __restrict__ enc,
                                                    float* __restrict__ ws)
{
    __shared__ f16 Bh[2][8*128*8], Bl[2][8*128*8];

    int tid = threadIdx.x;
    int w = __builtin_amdgcn_readfirstlane(tid >> 6);
    int l = tid & 63;
    int lane15 = l & 15, lg = l >> 4;
    int r0 = blockIdx.x * BM;
    int ky = blockIdx.y;
    int s_beg = (KS64 * ky) / KSPLIT;
    int s_end = (KS64 * (ky + 1)) / KSPLIT;

    const float* aptr0 = enc + (size_t)(r0 + w * 32 + lane15) * DDIM;
    const float* aptr1 = aptr0 + (size_t)16 * DDIM;
    const f16* bph = (const f16*)(ws + WS_BPH);
    const f16* bpl = (const f16*)(ws + WS_BPL);

    f32x4 acc[2][7] = {};
    float nsq0 = 0.f, nsq1 = 0.f;

    float4 ar[8];
    f16x8 bsh[2][2], bsl[2][2];

    #define LOAD_A(S) do {                                               \
        int kA_ = (S) * 64 + lg * 8;                                     \
        int kB_ = kA_ + 32;                                              \
        int a0_ = (kA_ + 4 <= DDIM) ? kA_ : 0;                           \
        int a1_ = (kA_ + 8 <= DDIM) ? (kA_ + 4) : 0;                     \
        int b0_ = (kB_ + 4 <= DDIM) ? kB_ : 0;                           \
        int b1_ = (kB_ + 8 <= DDIM) ? (kB_ + 4) : 0;                     \
        ar[0] = *(const float4*)(aptr0 + a0_);                           \
        ar[1] = *(const float4*)(aptr0 + a1_);                           \
        ar[2] = *(const float4*)(aptr0 + b0_);                           \
        ar[3] = *(const float4*)(aptr0 + b1_);                           \
        ar[4] = *(const float4*)(aptr1 + a0_);                           \
        ar[5] = *(const float4*)(aptr1 + a1_);                           \
        ar[6] = *(const float4*)(aptr1 + b0_);                           \
        ar[7] = *(const float4*)(aptr1 + b1_);                           \
    } while (0)

    #define LOAD_B(S) do {                                               \
        _Pragma("unroll")                                                \
        for (int j_ = 0; j_ < 2; ++j_) {                                 \
            size_t base_ = ((size_t)((S) * 8 + 2 * w + j_) * 128) * 8;   \
            bsh[j_][0] = *(const f16x8*)(bph + base_ + (size_t)l * 8);   \
            bsh[j_][1] = *(const f16x8*)(bph + base_ + (size_t)(l + 64) * 8); \
            bsl[j_][0] = *(const f16x8*)(bpl + base_ + (size_t)l * 8);   \
            bsl[j_][1] = *(const f16x8*)(bpl + base_ + (size_t)(l + 64) * 8); \
        }                                                                \
    } while (0)

    LOAD_A(s_beg);
    LOAD_B(s_beg);

    for (int S = s_beg; S < s_end; ++S) {
        int cur = S & 1;

        f16x8 ah[2][2], al[2][2];
        #pragma unroll
        for (int r = 0; r < 2; ++r) {
            float& nsq = r ? nsq1 : nsq0;
            #pragma unroll
            for (int ks = 0; ks < 2; ++ks) {
                float4 p0 = ar[r * 4 + ks * 2], p1 = ar[r * 4 + ks * 2 + 1];
                float v[8] = {p0.x, p0.y, p0.z, p0.w, p1.x, p1.y, p1.z, p1.w};
                int kb = S * 64 + ks * 32 + lg * 8;
                if (kb + 8 > DDIM) {
                    #pragma unroll
                    for (int j = 0; j < 8; ++j) if (kb + j >= DDIM) v[j] = 0.f;
                }
                #pragma unroll
                for (int j = 0; j < 8; ++j) {
                    f16 h = (f16)v[j];
                    ah[r][ks][j] = h;
                    al[r][ks][j] = (f16)(v[j] - (float)h);
                    nsq = fmaf(v[j], v[j], nsq);
                }
            }
        }

        #pragma unroll
        for (int j = 0; j < 2; ++j) {
            int kg = 2 * w + j;
            int s0 = kg * 128 + (l ^ kg);
            int s1 = kg * 128 + ((l + 64) ^ kg);
            *(f16x8*)&Bh[cur][s0 * 8] = bsh[j][0];
            *(f16x8*)&Bh[cur][s1 * 8] = bsh[j][1];
            *(f16x8*)&Bl[cur][s0 * 8] = bsl[j][0];
            *(f16x8*)&Bl[cur][s1 * 8] = bsl[j][1];
        }

        {
            int Sn = (S + 1 < s_end) ? (S + 1) : S;
            LOAD_A(Sn);
            LOAD_B(Sn);
        }

        SCHED();
        asm volatile("s_waitcnt lgkmcnt(0)" ::: "memory");
        SBAR();
        SCHED();

        #pragma unroll
        for (int ks = 0; ks < 2; ++ks) {
            int kg = ks * 4 + lg;
            #pragma unroll
            for (int nt = 0; nt < 7; ++nt) {
                int colS = (nt * 16 + lane15) ^ kg;
                f16x8 bh = *(const f16x8*)&Bh[cur][(kg * 128 + colS) * 8];
                f16x8 bl = *(const f16x8*)&Bl[cur][(kg * 128 + colS) * 8];
                acc[0][nt] = __builtin_amdgcn_mfma_f32_16x16x32_f16(ah[0][ks], bh, acc[0][nt], 0, 0, 0);
                acc[0][nt] = __builtin_amdgcn_mfma_f32_16x16x32_f16(al[0][ks], bh, acc[0][nt], 0, 0, 0);
                acc[0][nt] = __builtin_amdgcn_mfma_f32_16x16x32_f16(ah[0][ks], bl, acc[0][nt], 0, 0, 0);
                acc[1][nt] = __builtin_amdgcn_mfma_f32_16x16x32_f16(ah[1][ks], bh, acc[1][nt], 0, 0, 0);
                acc[1][nt] = __builtin_amdgcn_mfma_f32_16x16x32_f16(al[1][ks], bh, acc[1][nt], 0, 0, 0);
                acc[1][nt] = __builtin_amdgcn_mfma_f32_16x16x32_f16(ah[1][ks], bl, acc[1][nt], 0, 0, 0);
            }
        }
    }

    float* scp = ws + WS_SCP + (size_t)ky * SCORES_N;
    #pragma unroll
    for (int mt = 0; mt < 2; ++mt) {
        #pragma unroll
        for (int nt = 0; nt < 7; ++nt) {
            int gcol = nt * 16 + lane15;
            if (gcol < NCLS) {
                #pragma unroll
                for (int j = 0; j < 4; ++j) {
                    int grow = r0 + w * 32 + mt * 16 + lg * 4 + j;
                    scp[(size_t)grow * NCLS + gcol] = acc[mt][nt][j];
                }
            }
        }
    }

    nsq0 += __shfl_xor(nsq0, 16, 64);
    nsq0 += __shfl_xor(nsq0, 32, 64);
    nsq1 += __shfl_xor(nsq1, 16, 64);
    nsq1 += __shfl_xor(nsq1, 32, 64);
    if (l < 16) {
        ws[WS_NRM + (size_t)ky * NROWS + r0 + w * 32 + l] = nsq0;
        ws[WS_NRM + (size_t)ky * NROWS + r0 + w * 32 + 16 + l] = nsq1;
    }
}

// ---------------- Phase 2: finalize scores, argmax, write packed tp[] ----------------
__global__ __launch_bounds__(256) void finalize(const int* __restrict__ targets,
                                                float* __restrict__ out,
                                                float* __restrict__ ws)
{
    int w = threadIdx.x >> 6, l = threadIdx.x & 63;
    int row = blockIdx.x * 4 + w;
    const float* scp = ws + WS_SCP;

    float n2 = 0.f;
    #pragma unroll
    for (int ky = 0; ky < KSPLIT; ++ky) n2 += ws[WS_NRM + (size_t)ky * NROWS + row];
    float ne = sqrtf(n2);

    float best; int bi;
    {
        int c = l;
        float dsum = 0.f;
        #pragma unroll
        for (int ky = 0; ky < KSPLIT; ++ky)
            dsum += scp[(size_t)ky * SCORES_N + (size_t)row * NCLS + c];
        float s = dsum / (ne * ws[WS_NORMCLS + c]);
        out[(size_t)row * NCLS + c] = s;
        best = s; bi = c;
    }
    if (l + 64 < NCLS) {
        int c = l + 64;
        float dsum = 0.f;
        #pragma unroll
        for (int ky = 0; ky < KSPLIT; ++ky)
            dsum += scp[(size_t)ky * SCORES_N + (size_t)row * NCLS + c];
        float s = dsum / (ne * ws[WS_NORMCLS + c]);
        out[(size_t)row * NCLS + c] = s;
        if (s > best) { best = s; bi = c; }   // ties keep smaller index
    }
    #pragma unroll
    for (int off = 32; off; off >>= 1) {
        float ov = __shfl_xor(best, off, 64);
        int   oi = __shfl_xor(bi, off, 64);
        if (ov > best || (ov == best && oi < bi)) { best = ov; bi = oi; }
    }
    if (l == 0) {
        int tgt = targets[row];
        ((int*)ws)[WS_TP + row] = (tgt != bi) ? ((tgt << 8) | bi) : -1;
    }
}

// ---------------- Phase 3a: single-pass row scatter, 512-B bursts ----------------
// grid (79, 8); block 64 = 1 wave. Block: dims [128*bx,+128) as float2, rows
// [1024*ry,+1024). Per row: ONE 512-B contiguous wave load (vs R13's 256 B /
// R17's 128 B) -> DRAM page efficiency up (theory: scatter was burst-bound).
// Plain RMW on block-PRIVATE acc2[class][lane] (single wave, single writer,
// program order -> deterministic). Classes 100/101 = trash slots (branchless).
// NO LDS atomics (R15/R16: ds_add_f32 ~10x slower than plain RMW on gfx950).
__global__ __launch_bounds__(64) void update_scatter(const float* __restrict__ enc,
                                                     float* __restrict__ ws)
{
    __shared__ float2 acc2[102][UPD_DC / 2];   // 52.2 KB
    int l = threadIdx.x;                        // 0..63 = float2 slot

    for (int i = l; i < 102 * (UPD_DC / 2); i += 64)
        (&acc2[0][0])[i] = make_float2(0.f, 0.f);
    __syncthreads();

    int d0 = blockIdx.x * UPD_DC;
    int d2 = d0 / 2 + l;                               // float2 index in row
    int d2c = (2 * d2 + 1 < DDIM) ? d2 : (DDIM / 2 - 1);  // clamp: trash lanes
    const int* tp = ((const int*)ws) + WS_TP;
    int r0 = blockIdx.y * (NROWS / UPD_NY);
    const float2* ep2 = (const float2*)enc;             // row pitch DDIM/2

    float2 vA[16], vB[16];
    int tA[16], tB[16];

    #define UPD_ISSUE(BASE, V, T) do {                                  \
        _Pragma("unroll")                                               \
        for (int u_ = 0; u_ < 16; ++u_) {                               \
            int r_ = r0 + (BASE) + u_;                                  \
            (V)[u_] = ep2[(size_t)r_ * (DDIM / 2) + d2c];               \
            (T)[u_] = tp[r_];                                           \
        }                                                               \
    } while (0)

    #define UPD_PROC(V, T) do {                                         \
        _Pragma("unroll")                                               \
        for (int u_ = 0; u_ < 16; ++u_) {                               \
            int t_ = ((T)[u_] >= 0) ? ((T)[u_] >> 8)  : 100;            \
            int p_ = ((T)[u_] >= 0) ? ((T)[u_] & 255) : 101;            \
            float2 a_ = acc2[t_][l];                                    \
            a_.x += (V)[u_].x; a_.y += (V)[u_].y;                       \
            acc2[t_][l] = a_;                                           \
            float2 b_ = acc2[p_][l];                                    \
            b_.x -= (V)[u_].x; b_.y -= (V)[u_].y;                       \
            acc2[p_][l] = b_;                                           \
        }                                                               \
    } while (0)

    // 1024 rows, A/B 16-row batches keep 8 KB/wave of loads in flight
    UPD_ISSUE(0, vA, tA);
    for (int it = 0; it < (NROWS / UPD_NY) - 32; it += 32) {
        UPD_ISSUE(it + 16, vB, tB);
        UPD_PROC(vA, tA);
        UPD_ISSUE(it + 32, vA, tA);
        UPD_PROC(vB, tB);
    }
    // tail: last 16+16 rows
    UPD_ISSUE((NROWS / UPD_NY) - 16, vB, tB);
    UPD_PROC(vA, tA);
    UPD_PROC(vB, tB);
    __syncthreads();

    // write partials for this (row-chunk, dim-chunk)
    float* part = ws + WS_PART + (size_t)blockIdx.y * NCLS * DPAD;
    const float* af = (const float*)&acc2[0][0];
    for (int idx = l; idx < NCLS * UPD_DC; idx += 64) {
        int c = idx >> 7, dl2 = idx & 127;
        int dd = d0 + dl2;
        if (dd < DDIM)
            part[(size_t)c * DPAD + dd] = af[c * UPD_DC + dl2];
    }
}

// ---------------- Phase 3b: reduce UPD_NY partials + cls -> out ----------------
__global__ __launch_bounds__(256) void update_reduce(const float* __restrict__ cls,
                                                     float* __restrict__ out,
                                                     const float* __restrict__ ws)
{
    int idx = blockIdx.x * 256 + threadIdx.x;   // over NCLS * DDIM
    if (idx >= NCLS * DDIM) return;
    int c = idx / DDIM, d = idx - c * DDIM;
    const float* part = ws + WS_PART;
    size_t o = (size_t)c * DPAD + d;
    float s = 0.f;
    #pragma unroll
    for (int ry = 0; ry < UPD_NY; ++ry)
        s += part[(size_t)ry * NCLS * DPAD + o];
    out[SCORES_N + (size_t)c * DDIM + d] = cls[(size_t)c * DDIM + d] + s;
}

// ---------------- launch ----------------
extern "C" void kernel_launch(void* const* d_in, const int* in_sizes, int n_in,
                              void* d_out, int out_size, void* d_ws, size_t ws_size,
                              hipStream_t stream)
{
    const float* enc = (const float*)d_in[0];
    const float* cls = (const float*)d_in[1];
    const int*   tgt = (const int*)d_in[2];
    float* out = (float*)d_out;
    float* ws  = (float*)d_ws;

    prep<<<NCLS + PREPB_BLOCKS, 256, 0, stream>>>(cls, ws);

    dim3 g1(NROWS / BM, KSPLIT);
    gemm_mfma<<<g1, 256, 0, stream>>>(enc, ws);

    finalize<<<NROWS / 4, 256, 0, stream>>>(tgt, out, ws);

    dim3 g3((DDIM + UPD_DC - 1) / UPD_DC, UPD_NY);
    update_scatter<<<g3, 64, 0, stream>>>(enc, ws);

    update_reduce<<<(NCLS * DDIM + 255) / 256, 256, 0, stream>>>(cls, out, ws);
}

// Round 19
// 202.599 us; speedup vs baseline: 1.1651x; 1.1651x over previous
//
#include <hip/hip_runtime.h>
#include <hip/hip_bf16.h>
#include <math.h>

#define NROWS 8192
#define DDIM  10000
#define NCLS  100

#define KSPLIT 8
#define KS64   157            // 10048/64 k64-steps total
#define BM 128
#define UPD_DC 64             // dims per scatter block
#define DPAD 10048

#define SCORES_N (NROWS*NCLS)
#define NCHUNK8 1256          // k-octets, padded to 10048
#define BP_CHUNKS (NCHUNK8*128)
#define PREPB_BLOCKS ((BP_CHUNKS + 255) / 256)

// ws layout in float (4B) units
#define WS_NORMCLS 0                                   // 128
#define WS_NRM     128                                 // KSPLIT*NROWS
#define WS_SCP     (WS_NRM + KSPLIT*NROWS)             // KSPLIT*NROWS*NCLS
#define WS_TP      (WS_SCP + KSPLIT*SCORES_N)          // NROWS ints (packed tgt<<8|pred or -1)
#define WS_BPH     (WS_TP + NROWS + 128)               // BP_CHUNKS*4 floats (8 f16 each)
#define WS_BPL     (WS_BPH + BP_CHUNKS*4)
#define WS_PART    (WS_BPL + BP_CHUNKS*4)              // 4 * NCLS * DPAD floats

typedef _Float16 f16;
typedef f16 f16x8 __attribute__((ext_vector_type(8)));
typedef float f32x4 __attribute__((ext_vector_type(4)));

#define SBAR()  __builtin_amdgcn_s_barrier()
#define SCHED() __builtin_amdgcn_sched_barrier(0)

// ---------------- Phase 0 (fused): class norms + B prep ----------------
__global__ __launch_bounds__(256) void prep(const float* __restrict__ cls,
                                            float* __restrict__ ws)
{
    int bx = blockIdx.x;
    if (bx < NCLS) {
        int c = bx;
        const float* row = cls + (size_t)c * DDIM;
        float s = 0.f;
        for (int d = threadIdx.x; d < DDIM; d += 256) {
            float v = row[d];
            s = fmaf(v, v, s);
        }
        #pragma unroll
        for (int off = 32; off; off >>= 1) s += __shfl_xor(s, off, 64);
        __shared__ float red[4];
        int w = threadIdx.x >> 6, l = threadIdx.x & 63;
        if (l == 0) red[w] = s;
        __syncthreads();
        if (threadIdx.x == 0) {
            float t = red[0] + red[1] + red[2] + red[3];
            ws[WS_NORMCLS + c] = sqrtf(t);
        }
    } else {
        int c = (bx - NCLS) * 256 + threadIdx.x;
        if (c >= BP_CHUNKS) return;
        int col = c & 127, k8 = c >> 7;
        f16x8 hi, lo;
        #pragma unroll
        for (int j = 0; j < 8; ++j) {
            int k = k8 * 8 + j;
            float v = (col < NCLS && k < DDIM) ? cls[(size_t)col * DDIM + k] : 0.f;
            f16 h = (f16)v;
            hi[j] = h;
            lo[j] = (f16)(v - (float)h);
        }
        ((f16x8*)(ws + WS_BPH))[c] = hi;
        ((f16x8*)(ws + WS_BPL))[c] = lo;
    }
}

// ---------------- Phase 1: MFMA GEMM, BK=64 per stage ----------------
// XCD swizzle: grid (KSPLIT, NROWS/BM); ky = blockIdx.x -> dispatch round-robin
// pins all same-ky blocks to ONE XCD; that XCD's B-slice (2.5 MB hi+lo) fits
// its 4 MB L2 (vs all XCDs streaming the full 10 MB from L3).
__global__ __launch_bounds__(256, 2) void gemm_mfma(const float* __restrict__ enc,
                                                    float* __restrict__ ws)
{
    __shared__ f16 Bh[2][8*128*8], Bl[2][8*128*8];

    int tid = threadIdx.x;
    int w = __builtin_amdgcn_readfirstlane(tid >> 6);
    int l = tid & 63;
    int lane15 = l & 15, lg = l >> 4;
    int ky = blockIdx.x;                 // swizzled: ky is the FAST grid dim
    int r0 = blockIdx.y * BM;
    int s_beg = (KS64 * ky) / KSPLIT;
    int s_end = (KS64 * (ky + 1)) / KSPLIT;

    const float* aptr0 = enc + (size_t)(r0 + w * 32 + lane15) * DDIM;
    const float* aptr1 = aptr0 + (size_t)16 * DDIM;
    const f16* bph = (const f16*)(ws + WS_BPH);
    const f16* bpl = (const f16*)(ws + WS_BPL);

    f32x4 acc[2][7] = {};
    float nsq0 = 0.f, nsq1 = 0.f;

    float4 ar[8];
    f16x8 bsh[2][2], bsl[2][2];

    #define LOAD_A(S) do {                                               \
        int kA_ = (S) * 64 + lg * 8;                                     \
        int kB_ = kA_ + 32;                                              \
        int a0_ = (kA_ + 4 <= DDIM) ? kA_ : 0;                           \
        int a1_ = (kA_ + 8 <= DDIM) ? (kA_ + 4) : 0;                     \
        int b0_ = (kB_ + 4 <= DDIM) ? kB_ : 0;                           \
        int b1_ = (kB_ + 8 <= DDIM) ? (kB_ + 4) : 0;                     \
        ar[0] = *(const float4*)(aptr0 + a0_);                           \
        ar[1] = *(const float4*)(aptr0 + a1_);                           \
        ar[2] = *(const float4*)(aptr0 + b0_);                           \
        ar[3] = *(const float4*)(aptr0 + b1_);                           \
        ar[4] = *(const float4*)(aptr1 + a0_);                           \
        ar[5] = *(const float4*)(aptr1 + a1_);                           \
        ar[6] = *(const float4*)(aptr1 + b0_);                           \
        ar[7] = *(const float4*)(aptr1 + b1_);                           \
    } while (0)

    #define LOAD_B(S) do {                                               \
        _Pragma("unroll")                                                \
        for (int j_ = 0; j_ < 2; ++j_) {                                 \
            size_t base_ = ((size_t)((S) * 8 + 2 * w + j_) * 128) * 8;   \
            bsh[j_][0] = *(const f16x8*)(bph + base_ + (size_t)l * 8);   \
            bsh[j_][1] = *(const f16x8*)(bph + base_ + (size_t)(l + 64) * 8); \
            bsl[j_][0] = *(const f16x8*)(bpl + base_ + (size_t)l * 8);   \
            bsl[j_][1] = *(const f16x8*)(bpl + base_ + (size_t)(l + 64) * 8); \
        }                                                                \
    } while (0)

    LOAD_A(s_beg);
    LOAD_B(s_beg);

    for (int S = s_beg; S < s_end; ++S) {
        int cur = S & 1;

        f16x8 ah[2][2], al[2][2];
        #pragma unroll
        for (int r = 0; r < 2; ++r) {
            float& nsq = r ? nsq1 : nsq0;
            #pragma unroll
            for (int ks = 0; ks < 2; ++ks) {
                float4 p0 = ar[r * 4 + ks * 2], p1 = ar[r * 4 + ks * 2 + 1];
                float v[8] = {p0.x, p0.y, p0.z, p0.w, p1.x, p1.y, p1.z, p1.w};
                int kb = S * 64 + ks * 32 + lg * 8;
                if (kb + 8 > DDIM) {
                    #pragma unroll
                    for (int j = 0; j < 8; ++j) if (kb + j >= DDIM) v[j] = 0.f;
                }
                #pragma unroll
                for (int j = 0; j < 8; ++j) {
                    f16 h = (f16)v[j];
                    ah[r][ks][j] = h;
                    al[r][ks][j] = (f16)(v[j] - (float)h);
                    nsq = fmaf(v[j], v[j], nsq);
                }
            }
        }

        #pragma unroll
        for (int j = 0; j < 2; ++j) {
            int kg = 2 * w + j;
            int s0 = kg * 128 + (l ^ kg);
            int s1 = kg * 128 + ((l + 64) ^ kg);
            *(f16x8*)&Bh[cur][s0 * 8] = bsh[j][0];
            *(f16x8*)&Bh[cur][s1 * 8] = bsh[j][1];
            *(f16x8*)&Bl[cur][s0 * 8] = bsl[j][0];
            *(f16x8*)&Bl[cur][s1 * 8] = bsl[j][1];
        }

        {
            int Sn = (S + 1 < s_end) ? (S + 1) : S;
            LOAD_A(Sn);
            LOAD_B(Sn);
        }

        SCHED();
        asm volatile("s_waitcnt lgkmcnt(0)" ::: "memory");
        SBAR();
        SCHED();

        #pragma unroll
        for (int ks = 0; ks < 2; ++ks) {
            int kg = ks * 4 + lg;
            #pragma unroll
            for (int nt = 0; nt < 7; ++nt) {
                int colS = (nt * 16 + lane15) ^ kg;
                f16x8 bh = *(const f16x8*)&Bh[cur][(kg * 128 + colS) * 8];
                f16x8 bl = *(const f16x8*)&Bl[cur][(kg * 128 + colS) * 8];
                acc[0][nt] = __builtin_amdgcn_mfma_f32_16x16x32_f16(ah[0][ks], bh, acc[0][nt], 0, 0, 0);
                acc[0][nt] = __builtin_amdgcn_mfma_f32_16x16x32_f16(al[0][ks], bh, acc[0][nt], 0, 0, 0);
                acc[0][nt] = __builtin_amdgcn_mfma_f32_16x16x32_f16(ah[0][ks], bl, acc[0][nt], 0, 0, 0);
                acc[1][nt] = __builtin_amdgcn_mfma_f32_16x16x32_f16(ah[1][ks], bh, acc[1][nt], 0, 0, 0);
                acc[1][nt] = __builtin_amdgcn_mfma_f32_16x16x32_f16(al[1][ks], bh, acc[1][nt], 0, 0, 0);
                acc[1][nt] = __builtin_amdgcn_mfma_f32_16x16x32_f16(ah[1][ks], bl, acc[1][nt], 0, 0, 0);
            }
        }
    }

    float* scp = ws + WS_SCP + (size_t)ky * SCORES_N;
    #pragma unroll
    for (int mt = 0; mt < 2; ++mt) {
        #pragma unroll
        for (int nt = 0; nt < 7; ++nt) {
            int gcol = nt * 16 + lane15;
            if (gcol < NCLS) {
                #pragma unroll
                for (int j = 0; j < 4; ++j) {
                    int grow = r0 + w * 32 + mt * 16 + lg * 4 + j;
                    scp[(size_t)grow * NCLS + gcol] = acc[mt][nt][j];
                }
            }
        }
    }

    nsq0 += __shfl_xor(nsq0, 16, 64);
    nsq0 += __shfl_xor(nsq0, 32, 64);
    nsq1 += __shfl_xor(nsq1, 16, 64);
    nsq1 += __shfl_xor(nsq1, 32, 64);
    if (l < 16) {
        ws[WS_NRM + (size_t)ky * NROWS + r0 + w * 32 + l] = nsq0;
        ws[WS_NRM + (size_t)ky * NROWS + r0 + w * 32 + 16 + l] = nsq1;
    }
}

// ---------------- Phase 2: finalize scores, argmax, write packed tp[] ----------------
__global__ __launch_bounds__(256) void finalize(const int* __restrict__ targets,
                                                float* __restrict__ out,
                                                float* __restrict__ ws)
{
    int w = threadIdx.x >> 6, l = threadIdx.x & 63;
    int row = blockIdx.x * 4 + w;
    const float* scp = ws + WS_SCP;

    float n2 = 0.f;
    #pragma unroll
    for (int ky = 0; ky < KSPLIT; ++ky) n2 += ws[WS_NRM + (size_t)ky * NROWS + row];
    float ne = sqrtf(n2);

    float best; int bi;
    {
        int c = l;
        float dsum = 0.f;
        #pragma unroll
        for (int ky = 0; ky < KSPLIT; ++ky)
            dsum += scp[(size_t)ky * SCORES_N + (size_t)row * NCLS + c];
        float s = dsum / (ne * ws[WS_NORMCLS + c]);
        out[(size_t)row * NCLS + c] = s;
        best = s; bi = c;
    }
    if (l + 64 < NCLS) {
        int c = l + 64;
        float dsum = 0.f;
        #pragma unroll
        for (int ky = 0; ky < KSPLIT; ++ky)
            dsum += scp[(size_t)ky * SCORES_N + (size_t)row * NCLS + c];
        float s = dsum / (ne * ws[WS_NORMCLS + c]);
        out[(size_t)row * NCLS + c] = s;
        if (s > best) { best = s; bi = c; }   // ties keep smaller index
    }
    #pragma unroll
    for (int off = 32; off; off >>= 1) {
        float ov = __shfl_xor(best, off, 64);
        int   oi = __shfl_xor(bi, off, 64);
        if (ov > best || (ov == best && oi < bi)) { best = ov; bi = oi; }
    }
    if (l == 0) {
        int tgt = targets[row];
        ((int*)ws)[WS_TP + row] = (tgt != bi) ? ((tgt << 8) | bi) : -1;
    }
}

// ---------------- Phase 3a: single-pass row scatter (R13 structure, 32-deep prefetch) ----------------
// grid (157, 4); block 128 = 2 waves. Wave wv owns 1024 rows; tp[r] wave-uniform ->
// plain RMW on wave-PRIVATE acc[wv][class][lane]; classes 100/101 = trash slots.
// Depth 32 (vs R13's 16): ~48 KB/CU of loads in flight covers HBM latency through
// the whole RMW phase. NO LDS atomics (R15/R16: ds_add_f32 ~10x slower than RMW).
__global__ __launch_bounds__(128) void update_scatter(const float* __restrict__ enc,
                                                      float* __restrict__ ws)
{
    __shared__ float acc[2][102][UPD_DC];   // 52.2 KB
    int tid = threadIdx.x;
    int wv = tid >> 6, l = tid & 63;

    for (int i = tid; i < 2 * 102 * UPD_DC; i += 128) (&acc[0][0][0])[i] = 0.f;
    __syncthreads();

    int d = blockIdx.x * UPD_DC + l;
    int dc = (d < DDIM) ? d : (DDIM - 1);     // OOB lanes compute trash, never written out
    const int* tp = ((const int*)ws) + WS_TP;
    int r0 = blockIdx.y * 2048 + wv * 1024;
    const float* ep = enc + dc;

    float vA[32], vB[32];
    int tA[32], tB[32];

    #define UPD_ISSUE(BASE, V, T) do {                                  \
        _Pragma("unroll")                                               \
        for (int u_ = 0; u_ < 32; ++u_) {                               \
            int r_ = r0 + (BASE) + u_;                                  \
            (V)[u_] = ep[(size_t)r_ * DDIM];                            \
            (T)[u_] = tp[r_];                                           \
        }                                                               \
    } while (0)

    #define UPD_PROC(V, T) do {                                         \
        _Pragma("unroll")                                               \
        for (int u_ = 0; u_ < 32; ++u_) {                               \
            int t_ = ((T)[u_] >= 0) ? ((T)[u_] >> 8)  : 100;            \
            int p_ = ((T)[u_] >= 0) ? ((T)[u_] & 255) : 101;            \
            acc[wv][t_][l] += (V)[u_];                                  \
            acc[wv][p_][l] -= (V)[u_];                                  \
        }                                                               \
    } while (0)

    UPD_ISSUE(0, vA, tA);
    for (int it = 0; it < 1024 - 64; it += 64) {
        UPD_ISSUE(it + 32, vB, tB);
        UPD_PROC(vA, tA);
        UPD_ISSUE(it + 64, vA, tA);
        UPD_PROC(vB, tB);
    }
    // tail: rows [960,1024): vA=[960..991] already issued
    UPD_ISSUE(992, vB, tB);
    UPD_PROC(vA, tA);
    UPD_PROC(vB, tB);
    __syncthreads();

    // write partials for this (row-chunk, dim-chunk)
    float* part = ws + WS_PART + (size_t)blockIdx.y * NCLS * DPAD;
    for (int idx = tid; idx < NCLS * UPD_DC; idx += 128) {
        int c = idx >> 6, dl = idx & 63;
        int dd = blockIdx.x * UPD_DC + dl;
        if (dd < DDIM)
            part[(size_t)c * DPAD + dd] = acc[0][c][dl] + acc[1][c][dl];
    }
}

// ---------------- Phase 3b: reduce 4 partials + cls -> out ----------------
__global__ __launch_bounds__(256) void update_reduce(const float* __restrict__ cls,
                                                     float* __restrict__ out,
                                                     const float* __restrict__ ws)
{
    int idx = blockIdx.x * 256 + threadIdx.x;   // over NCLS * DDIM
    if (idx >= NCLS * DDIM) return;
    int c = idx / DDIM, d = idx - c * DDIM;
    const float* part = ws + WS_PART;
    size_t o = (size_t)c * DPAD + d;
    float s = part[o] + part[(size_t)1 * NCLS * DPAD + o]
            + part[(size_t)2 * NCLS * DPAD + o] + part[(size_t)3 * NCLS * DPAD + o];
    out[SCORES_N + (size_t)c * DDIM + d] = cls[(size_t)c * DDIM + d] + s;
}

// ---------------- launch ----------------
extern "C" void kernel_launch(void* const* d_in, const int* in_sizes, int n_in,
                              void* d_out, int out_size, void* d_ws, size_t ws_size,
                              hipStream_t stream)
{
    const float* enc = (const float*)d_in[0];
    const float* cls = (const float*)d_in[1];
    const int*   tgt = (const int*)d_in[2];
    float* out = (float*)d_out;
    float* ws  = (float*)d_ws;

    prep<<<NCLS + PREPB_BLOCKS, 256, 0, stream>>>(cls, ws);

    dim3 g1(KSPLIT, NROWS / BM);   // XCD swizzle: ky fast -> same-ky on same XCD
    gemm_mfma<<<g1, 256, 0, stream>>>(enc, ws);

    finalize<<<NROWS / 4, 256, 0, stream>>>(tgt, out, ws);

    dim3 g3((DDIM + UPD_DC - 1) / UPD_DC, 4);
    update_scatter<<<g3, 128, 0, stream>>>(enc, ws);

    update_reduce<<<(NCLS * DDIM + 255) / 256, 256, 0, stream>>>(cls, out, ws);
}